// Round 1
// 263.748 us; speedup vs baseline: 1.0220x; 1.0220x over previous
//
#include <hip/hip_runtime.h>
#include <hip/hip_bf16.h>
#include <cstdint>
#include <cstddef>

#define NTOK 8192
#define DIM  1024
#define NEXP 64
#define RANK 64
#define NGRP 8
#define NLOC 8

typedef __attribute__((ext_vector_type(8))) short bf16x8;
typedef __attribute__((ext_vector_type(4))) float f32x4;

static __device__ inline unsigned int pack_bf16x2(float a, float b) {
    __hip_bfloat16 ha = __float2bfloat16(a);
    __hip_bfloat16 hb = __float2bfloat16(b);
    return (unsigned int)(*(unsigned short*)&ha) |
           ((unsigned int)(*(unsigned short*)&hb) << 16);
}

// ---------------------------------------------------------------------------
// Fused scoring + routing:
//   Phase A: group scores (fp32-exact) + h -> bf16 cast (as before).
//   Phase B: local scores for the SELECTED group only, reading h (L2-hot,
//            just read by phase A; loop runs k backwards for LRU locality)
//            and Wloc (256 KB total, L2-resident) straight from global.
//   Then top-2 + softmax + expert histogram (old route2) in-block.
// Eliminates scatter_g, score_loc (33.5 MB gathered h re-read), route2,
// and the S_loc/glist round trips. fp32 throughout scoring: argmax/top-2
// selection must be bit-comparable to the verified path.
// ---------------------------------------------------------------------------
__global__ __launch_bounds__(256, 4) void score_fused(
    const float* __restrict__ h, const float* __restrict__ Wg,
    const float* __restrict__ bg, const float* __restrict__ Wloc,
    unsigned short* __restrict__ hb, float* __restrict__ out_gidx,
    float* __restrict__ out_eid, float* __restrict__ out_gate,
    int* __restrict__ ws_eids, float* __restrict__ ws_gates,
    int* __restrict__ counts_e)
{
    __shared__ float Hs[16][66];
    __shared__ float Bs[64 * 8];
    __shared__ float Sp[16][16][8];   // [t][kq][m]
    __shared__ float Sg[16][9];       // phase A: group scores; phase B: local scores
    __shared__ int   gsel[16];

    const int t0  = blockIdx.x * 16;
    const int tid = threadIdx.x;
    const int t   = tid & 15;
    const int kq  = tid >> 4;
    const int kbase = (kq >> 2) * 16 + (kq & 3);

    // ---- Phase A: group scores + bf16 cast (identical to verified kernel) ----
    float acc[8] = {};
    for (int kc = 0; kc < DIM; kc += 64) {
        __syncthreads();
        {   // stage Hs + emit bf16 cast (one float4 per thread)
            const int r = tid >> 4, c4 = tid & 15;
            const float4 v = *(const float4*)(h + (size_t)(t0 + r) * DIM + kc + c4 * 4);
            *(float2*)&Hs[r][c4 * 4]     = make_float2(v.x, v.y);
            *(float2*)&Hs[r][c4 * 4 + 2] = make_float2(v.z, v.w);
            uint2 pk;
            pk.x = pack_bf16x2(v.x, v.y);
            pk.y = pack_bf16x2(v.z, v.w);
            *(uint2*)(hb + (size_t)(t0 + r) * DIM + kc + c4 * 4) = pk;
        }
        {   // stage Bs: Wg chunk (64 k x 8 g), contiguous 512 floats
            const float* src = Wg + (size_t)kc * NGRP;
            Bs[tid] = src[tid];
            Bs[tid + 256] = src[tid + 256];
        }
        __syncthreads();
#pragma unroll
        for (int kk = 0; kk < 4; ++kk) {
            const int k = kbase + kk * 4;
            const float a = Hs[t][k];
            const float4 b0 = *(const float4*)&Bs[k * 8];
            const float4 b1 = *(const float4*)&Bs[k * 8 + 4];
            acc[0] += a * b0.x; acc[1] += a * b0.y; acc[2] += a * b0.z; acc[3] += a * b0.w;
            acc[4] += a * b1.x; acc[5] += a * b1.y; acc[6] += a * b1.z; acc[7] += a * b1.w;
        }
    }
#pragma unroll
    for (int m = 0; m < 8; ++m) Sp[t][kq][m] = acc[m];
    __syncthreads();
    if (tid < 128) {
        const int tt = tid >> 3, m = tid & 7;
        float s = 0.f;
#pragma unroll
        for (int q = 0; q < 16; ++q) s += Sp[tt][q][m];
        Sg[tt][m] = s + bg[m];
    }
    __syncthreads();
    if (tid < 16) {
        int gi = 0; float best = Sg[tid][0];
#pragma unroll
        for (int g = 1; g < NGRP; ++g) {
            if (Sg[tid][g] > best) { best = Sg[tid][g]; gi = g; }
        }
        out_gidx[t0 + tid] = (float)gi;
        gsel[tid] = gi;
    }
    __syncthreads();   // gsel visible; Sp/Sg free for reuse

    // ---- Phase B: local scores for selected group (h from L2, Wloc from L2) ----
    {
        const int gsel_t = gsel[t];
        const float* wl = Wloc + (size_t)gsel_t * DIM * NLOC;
        const float* hrow = h + (size_t)(t0 + t) * DIM;
        float acc2[8] = {};
        // backwards: tail of the h row was read most recently by phase A
        for (int kc = DIM - 64; kc >= 0; kc -= 64) {
            const int k0 = kc + kq * 4;
            const f32x4 hv = *(const f32x4*)(hrow + k0);
#pragma unroll
            for (int kk = 0; kk < 4; ++kk) {
                const float a = hv[kk];
                const float4 b0 = *(const float4*)(wl + (size_t)(k0 + kk) * NLOC);
                const float4 b1 = *(const float4*)(wl + (size_t)(k0 + kk) * NLOC + 4);
                acc2[0] += a * b0.x; acc2[1] += a * b0.y; acc2[2] += a * b0.z; acc2[3] += a * b0.w;
                acc2[4] += a * b1.x; acc2[5] += a * b1.y; acc2[6] += a * b1.z; acc2[7] += a * b1.w;
            }
        }
#pragma unroll
        for (int m = 0; m < 8; ++m) Sp[t][kq][m] = acc2[m];
    }
    __syncthreads();
    if (tid < 128) {
        const int tt = tid >> 3, m = tid & 7;
        float s = 0.f;
#pragma unroll
        for (int q = 0; q < 16; ++q) s += Sp[tt][q][m];
        Sg[tt][m] = s;   // local scores (no bias)
    }
    __syncthreads();

    // ---- top-2 + softmax + outputs (old route2, np first-index-wins ties) ----
    if (tid < 16) {
        const int tok = t0 + tid;
        float ls[NLOC];
#pragma unroll
        for (int m = 0; m < NLOC; ++m) ls[m] = Sg[tid][m];

        int m1 = 0; float v1 = ls[0];
#pragma unroll
        for (int m = 1; m < NLOC; ++m) { if (ls[m] > v1) { v1 = ls[m]; m1 = m; } }
        int m2 = (m1 == 0) ? 1 : 0; float v2 = ls[m2];
#pragma unroll
        for (int m = 0; m < NLOC; ++m) {
            if (m != m1 && m != ((m1 == 0) ? 1 : 0) && ls[m] > v2) { v2 = ls[m]; m2 = m; }
        }
        const float e2v = expf(v2 - v1);
        const float inv = 1.f / (1.f + e2v);
        const float g0 = inv, g1 = e2v * inv;
        const int gi = gsel[tid];
        const int ea = gi * NLOC + m1, eb = gi * NLOC + m2;

        out_eid[tok * 2 + 0] = (float)ea;
        out_eid[tok * 2 + 1] = (float)eb;
        out_gate[tok * 2 + 0] = g0;
        out_gate[tok * 2 + 1] = g1;
        ws_eids[tok * 2 + 0] = ea;
        ws_eids[tok * 2 + 1] = eb;
        ws_gates[tok * 2 + 0] = g0;
        ws_gates[tok * 2 + 1] = g1;
        atomicAdd(&counts_e[ea], 1);
        atomicAdd(&counts_e[eb], 1);
    }
}

// ---------------------------------------------------------------------------
// Scatter (token, slot-rank j) into per-expert buckets. The 64-wide exclusive
// scan over counts_e is recomputed in-block (L1/L2-hot, ~10 instr) — the
// former 1-block scan_kernel was a full-device serialization bubble.
// ---------------------------------------------------------------------------
__global__ __launch_bounds__(256) void scatter_e(
    const int* __restrict__ ws_eids, const float* __restrict__ ws_gates,
    const int* __restrict__ counts_e, int* __restrict__ cursor,
    int* __restrict__ token_list, float* __restrict__ slot_gate)
{
    __shared__ int offS[64];
    const int tid = threadIdx.x;
    if (tid < 64) {
        const int c = counts_e[tid];
        int s = c;
#pragma unroll
        for (int d = 1; d < 64; d <<= 1) {
            int v = __shfl_up(s, d, 64);
            if (tid >= d) s += v;
        }
        offS[tid] = s - c;
    }
    __syncthreads();
    const int t = blockIdx.x * 256 + tid;
    if (t >= NTOK) return;
#pragma unroll
    for (int j = 0; j < 2; ++j) {
        const int eid = ws_eids[t * 2 + j];
        const int pos = offS[eid] + atomicAdd(&cursor[eid], 1);
        token_list[pos] = t * 2 + j;
        slot_gate[pos] = ws_gates[t * 2 + j];
    }
}

// ---------------------------------------------------------------------------
// prep_w: merged W1 and W2 transpose+cast. y<16 -> W1 [e][k][r] -> [e][r][k];
// y>=16 -> W2 [e][r][d] -> [e][d][r]. (One launch instead of two.)
// ---------------------------------------------------------------------------
__global__ __launch_bounds__(256) void prep_w(
    const float* __restrict__ W1, const float* __restrict__ W2,
    unsigned short* __restrict__ W1t, unsigned short* __restrict__ W2t)
{
    __shared__ float Ls[64][65];
    const int e = blockIdx.x;
    const int y = blockIdx.y;
    if (y < 16) {
        const int kb = y;
        const float* src = W1 + (size_t)e * DIM * RANK + (size_t)kb * 64 * RANK;
#pragma unroll
        for (int it = 0; it < 4; ++it) {
            const int kk = (threadIdx.x >> 4) + it * 16;
            const int rr = (threadIdx.x & 15) * 4;
            *(float4*)&Ls[kk][rr] = *(const float4*)(src + (size_t)kk * RANK + rr);
        }
        __syncthreads();
#pragma unroll
        for (int it = 0; it < 2; ++it) {
            const int idx = threadIdx.x + it * 256;
            const int r = idx >> 3, k8 = (idx & 7) * 8;
            uint4 v;
            v.x = pack_bf16x2(Ls[k8 + 0][r], Ls[k8 + 1][r]);
            v.y = pack_bf16x2(Ls[k8 + 2][r], Ls[k8 + 3][r]);
            v.z = pack_bf16x2(Ls[k8 + 4][r], Ls[k8 + 5][r]);
            v.w = pack_bf16x2(Ls[k8 + 6][r], Ls[k8 + 7][r]);
            *(uint4*)(W1t + (size_t)e * RANK * DIM + (size_t)r * DIM + kb * 64 + k8) = v;
        }
    } else {
        const int db = y - 16;
        const float* src = W2 + (size_t)e * RANK * DIM + db * 64;
#pragma unroll
        for (int it = 0; it < 4; ++it) {
            const int rr = (threadIdx.x >> 4) + it * 16;
            const int dd = (threadIdx.x & 15) * 4;
            *(float4*)&Ls[rr][dd] = *(const float4*)(src + (size_t)rr * DIM + dd);
        }
        __syncthreads();
#pragma unroll
        for (int it = 0; it < 2; ++it) {
            const int idx = threadIdx.x + it * 256;
            const int d = idx >> 3, r8 = (idx & 7) * 8;
            uint4 v;
            v.x = pack_bf16x2(Ls[r8 + 0][d], Ls[r8 + 1][d]);
            v.y = pack_bf16x2(Ls[r8 + 2][d], Ls[r8 + 3][d]);
            v.z = pack_bf16x2(Ls[r8 + 4][d], Ls[r8 + 5][d]);
            v.w = pack_bf16x2(Ls[r8 + 6][d], Ls[r8 + 7][d]);
            *(uint4*)(W2t + (size_t)e * DIM * RANK + (size_t)(db * 64 + d) * RANK + r8) = v;
        }
    }
}

// ---------------------------------------------------------------------------
// E1 (MFMA): P[slot][r] = bf16( gate * relu(h[tok] @ W1[e]) ).
// Expert offsets recomputed in-block from counts_e (scan kernel removed).
// ---------------------------------------------------------------------------
__global__ __launch_bounds__(256, 2) void e1_mfma(
    const unsigned short* __restrict__ hb, const unsigned short* __restrict__ W1t,
    const int* __restrict__ counts_e, const int* __restrict__ token_list,
    const float* __restrict__ slot_gate, unsigned short* __restrict__ P)
{
    __shared__ unsigned short Hs[64 * 72];
    __shared__ unsigned short Ws[64 * 72];
    __shared__ int   tokS[64];
    __shared__ float gateS[64];
    __shared__ int   offS[65];

    const int e   = blockIdx.x;
    const int tid = threadIdx.x;
    if (tid < 64) {
        const int c = counts_e[tid];
        int s = c;
#pragma unroll
        for (int d = 1; d < 64; d <<= 1) {
            int v = __shfl_up(s, d, 64);
            if (tid >= d) s += v;
        }
        offS[tid] = s - c;
        if (tid == 63) offS[64] = s;
    }
    __syncthreads();
    const int n0 = offS[e];
    const int ne = offS[e + 1] - n0;

    const unsigned short* W1te = W1t + (size_t)e * RANK * DIM;
    const int wave = tid >> 6;
    const int lane = tid & 63;
    const int tx   = lane & 15;
    const int quad = lane >> 4;

    for (int tile = blockIdx.y; tile * 64 < ne; tile += 8) {
        const int row0 = tile * 64;
        __syncthreads();
        if (tid < 64) {
            const int gr = row0 + tid;
            tokS[tid]  = (gr < ne) ? token_list[n0 + gr] : -1;
            gateS[tid] = (gr < ne) ? slot_gate[n0 + gr] : 0.f;
        }
        f32x4 acc[4] = {};
        for (int kc = 0; kc < DIM; kc += 64) {
            __syncthreads();
#pragma unroll
            for (int it = 0; it < 2; ++it) {
                const int idx = tid + it * 256;
                const int s = idx >> 3, k8 = (idx & 7) * 8;
                const int ent = tokS[s];
                uint4 v = make_uint4(0, 0, 0, 0);
                if (ent >= 0)
                    v = *(const uint4*)(hb + (size_t)(ent >> 1) * DIM + kc + k8);
                *(uint4*)(Hs + s * 72 + k8) = v;
            }
#pragma unroll
            for (int it = 0; it < 2; ++it) {
                const int idx = tid + it * 256;
                const int r = idx >> 3, k8 = (idx & 7) * 8;
                *(uint4*)(Ws + r * 72 + k8) =
                    *(const uint4*)(W1te + (size_t)r * DIM + kc + k8);
            }
            __syncthreads();
#pragma unroll
            for (int ks = 0; ks < 2; ++ks) {
                const bf16x8 a = *(const bf16x8*)(Hs + (wave * 16 + tx) * 72 + ks * 32 + quad * 8);
#pragma unroll
                for (int j = 0; j < 4; ++j) {
                    const bf16x8 b = *(const bf16x8*)(Ws + (j * 16 + tx) * 72 + ks * 32 + quad * 8);
                    acc[j] = __builtin_amdgcn_mfma_f32_16x16x32_bf16(a, b, acc[j], 0, 0, 0);
                }
            }
        }
#pragma unroll
        for (int j = 0; j < 4; ++j) {
#pragma unroll
            for (int i = 0; i < 4; ++i) {
                const int sl = wave * 16 + quad * 4 + i;
                const int gr = row0 + sl;
                if (gr < ne) {
                    const float v = fmaxf(acc[j][i], 0.f) * gateS[sl];
                    __hip_bfloat16 hv = __float2bfloat16(v);
                    P[(size_t)(n0 + gr) * RANK + j * 16 + tx] = *(unsigned short*)&hv;
                }
            }
        }
    }
}

// ---------------------------------------------------------------------------
// E2 (MFMA): C = P[slot] @ W2[e]; j=0 -> out[tok], j=1 -> contrib[tok].
// ---------------------------------------------------------------------------
__global__ __launch_bounds__(256, 2) void e2_mfma(
    const unsigned short* __restrict__ P, const unsigned short* __restrict__ W2t,
    const int* __restrict__ counts_e, const int* __restrict__ token_list,
    float* __restrict__ out, float* __restrict__ contrib)
{
    __shared__ unsigned short Ps[64 * 72];
    __shared__ unsigned short W2s[64 * 72];
    __shared__ int tokS[64];
    __shared__ int offS[65];

    const int e = blockIdx.x;
    const int colbase = blockIdx.y * 64;
    const int tid = threadIdx.x;
    if (tid < 64) {
        const int c = counts_e[tid];
        int s = c;
#pragma unroll
        for (int d = 1; d < 64; d <<= 1) {
            int v = __shfl_up(s, d, 64);
            if (tid >= d) s += v;
        }
        offS[tid] = s - c;
        if (tid == 63) offS[64] = s;
    }
    __syncthreads();
    const int n0 = offS[e];
    const int ne = offS[e + 1] - n0;

    const unsigned short* W2te = W2t + (size_t)e * DIM * RANK;
    const int wave = tid >> 6;
    const int lane = tid & 63;
    const int tx   = lane & 15;
    const int quad = lane >> 4;

#pragma unroll
    for (int it = 0; it < 2; ++it) {
        const int idx = tid + it * 256;
        const int d = idx >> 3, r8 = (idx & 7) * 8;
        *(uint4*)(W2s + d * 72 + r8) =
            *(const uint4*)(W2te + (size_t)(colbase + d) * RANK + r8);
    }

    for (int tile = blockIdx.z; tile * 64 < ne; tile += 4) {
        const int row0 = tile * 64;
        __syncthreads();
        if (tid < 64) {
            const int gr = row0 + tid;
            tokS[tid] = (gr < ne) ? token_list[n0 + gr] : -1;
        }
#pragma unroll
        for (int it = 0; it < 2; ++it) {
            const int idx = tid + it * 256;
            const int s = idx >> 3, r8 = (idx & 7) * 8;
            const int gr = row0 + s;
            uint4 v = make_uint4(0, 0, 0, 0);
            if (gr < ne) v = *(const uint4*)(P + (size_t)(n0 + gr) * RANK + r8);
            *(uint4*)(Ps + s * 72 + r8) = v;
        }
        __syncthreads();
        f32x4 acc[4] = {};
#pragma unroll
        for (int ks = 0; ks < 2; ++ks) {
            const bf16x8 a = *(const bf16x8*)(Ps + (wave * 16 + tx) * 72 + ks * 32 + quad * 8);
#pragma unroll
            for (int j = 0; j < 4; ++j) {
                const bf16x8 b = *(const bf16x8*)(W2s + (j * 16 + tx) * 72 + ks * 32 + quad * 8);
                acc[j] = __builtin_amdgcn_mfma_f32_16x16x32_bf16(a, b, acc[j], 0, 0, 0);
            }
        }
#pragma unroll
        for (int i = 0; i < 4; ++i) {
            const int sl = wave * 16 + quad * 4 + i;
            const int ent = tokS[sl];
            if (ent >= 0) {
                float* base = (ent & 1) ? contrib : out;
                float* op = base + (size_t)(ent >> 1) * DIM + colbase;
#pragma unroll
                for (int j = 0; j < 4; ++j)
                    op[j * 16 + tx] = acc[j][i];
            }
        }
    }
}

// ---------------------------------------------------------------------------
__global__ __launch_bounds__(256) void combine_kernel(
    const float* __restrict__ contrib, float* __restrict__ out)
{
    const size_t i = (size_t)blockIdx.x * 256 + threadIdx.x;
    float4 a = ((const float4*)out)[i];
    const float4 b = ((const float4*)contrib)[i];
    a.x += b.x; a.y += b.y; a.z += b.z; a.w += b.w;
    ((float4*)out)[i] = a;
}

// ---------------------------------------------------------------------------
extern "C" void kernel_launch(void* const* d_in, const int* in_sizes, int n_in,
                              void* d_out, int out_size, void* d_ws, size_t ws_size,
                              hipStream_t stream)
{
    const float* h    = (const float*)d_in[0];
    const float* Wg   = (const float*)d_in[1];
    const float* bg   = (const float*)d_in[2];
    const float* Wloc = (const float*)d_in[3];
    const float* W1   = (const float*)d_in[4];
    const float* W2   = (const float*)d_in[5];

    float* out_f    = (float*)d_out;
    float* out_main = out_f;
    float* out_eid  = out_f + (size_t)NTOK * DIM;
    float* out_gate = out_eid + (size_t)NTOK * 2;
    float* out_gidx = out_gate + (size_t)NTOK * 2;

    int* ws_i        = (int*)d_ws;
    int* counts_e    = ws_i;                  // [0,64)
    int* cursor_e    = ws_i + 192;            // [192,256)
    int* ws_eids     = ws_i + 16896;          // 16384
    int* token_list  = ws_i + 33280;          // 16384
    float* ws_f      = (float*)(ws_i + 49664);
    float* ws_gates  = ws_f;                  // 16384
    float* slot_gate = ws_f + 16384;          // 16384
    unsigned short* P_h = (unsigned short*)(ws_f + 2 * 16384 + 65536);  // 2 MB
    unsigned short* W1t = P_h + (size_t)16384 * RANK;                   // 8 MB
    unsigned short* W2t = W1t + (size_t)NEXP * RANK * DIM;              // 8 MB
    float* contrib      = (float*)(W2t + (size_t)NEXP * DIM * RANK);    // 32 MB
    // hb (16.8 MB) aliases contrib: written by score_fused, read by e1,
    // clobbered by e2's contrib stores (e1 complete by then; stream-serial).
    unsigned short* hb = (unsigned short*)contrib;

    hipMemsetAsync(ws_i, 0, 256 * sizeof(int), stream);

    prep_w<<<dim3(NEXP, 32), 256, 0, stream>>>(W1, W2, W1t, W2t);
    score_fused<<<NTOK / 16, 256, 0, stream>>>(h, Wg, bg, Wloc, hb,
        out_gidx, out_eid, out_gate, ws_eids, ws_gates, counts_e);
    scatter_e<<<NTOK / 256, 256, 0, stream>>>(ws_eids, ws_gates, counts_e,
        cursor_e, token_list, slot_gate);
    e1_mfma<<<dim3(NEXP, 8), 256, 0, stream>>>(hb, W1t, counts_e, token_list,
        slot_gate, P_h);
    e2_mfma<<<dim3(NEXP, 16, 4), 256, 0, stream>>>(P_h, W2t, counts_e, token_list,
        out_main, contrib);
    combine_kernel<<<(NTOK * DIM / 4) / 256, 256, 0, stream>>>(contrib, out_main);
}